// Round 12
// baseline (56.846 us; speedup 1.0000x reference)
//
#include <hip/hip_runtime.h>
#include <hip/hip_bf16.h>
#include <cstdint>
#include <cstddef>

// B=8, T=2048, D=128 causal dual-mode attention.
// logits = Qeff . K^T with Qeff[t][d] = -alpha*scale*q[t][d] + (1-alpha)*scale*q[t][(d+1)%D]
// (feature-roll moved from K onto Q), then causal softmax, then @V.
//
// R12: R11 + double-buffering + mt=2 K/V-fragment reuse.
// 2-wave (128t) blocks, 64 q-rows (32/wave), KVBLK=32 double-buffered in 36KB
// LDS -> 4 blocks/CU (8 waves/CU, 4 independent barrier groups), stage-next
// overlaps compute (one barrier/step). SEGT=8 split-KV (576 live blocks, all
// co-resident). Defer-max + deferred-sum softmax in exp2 domain.

typedef __attribute__((ext_vector_type(8))) short short8;
typedef __attribute__((ext_vector_type(4))) float f32x4;

#define T_DIM 2048
#define D_DIM 128
#define B_DIM 8
#define SEGT 8              // 32-kv tiles per segment
#define POSLOTS_PER_B 112   // sum over c=0..31 of (nseg(c)-1), nseg=(c+4)>>2
#define MLSLOTS_PER_B 144   // sum of nseg(c) = 112 + 32
#define LOG2E 1.4426950408889634f

__device__ __forceinline__ unsigned short f2bf(float f) {
  unsigned u = __builtin_bit_cast(unsigned, f);
  u += 0x7FFFu + ((u >> 16) & 1u);          // RNE
  return (unsigned short)(u >> 16);
}
__device__ __forceinline__ float bf2f(unsigned short u) {
  return __uint_as_float(((unsigned)u) << 16);
}
__device__ __forceinline__ void gload_lds16(const void* g, void* l) {
  __builtin_amdgcn_global_load_lds(
      (const __attribute__((address_space(1))) unsigned int*)g,
      (__attribute__((address_space(3))) unsigned int*)l, 16, 0, 0);
}

// ---------------- fused prepass: K->bf16, Qeff->bf16 (log2e folded), V^T->bf16 ----------------
__global__ __launch_bounds__(256) void prep_all(
    const float* __restrict__ q, const float* __restrict__ k, const float* __restrict__ v,
    const float* __restrict__ modep,
    unsigned short* __restrict__ qbf, unsigned short* __restrict__ kbf,
    unsigned short* __restrict__ vt)
{
  __shared__ unsigned short tile[64 * 136];   // V rows as bf16, pitch 136 shorts
  const int b = blockIdx.x, s0 = blockIdx.y * 64;
  const int tid = threadIdx.x;
  const float alpha = 1.f / (1.f + __expf(-modep[0]));
  const float scale = 0.08838834764831845f;
  const float ca = -alpha * scale * LOG2E, cb = (1.f - alpha) * scale * LOG2E;

#pragma unroll
  for (int u = 0; u < 4; ++u) {
    int c = u * 256 + tid;                    // 1024 chunks = 64 rows x 16
    int r = c >> 4, c8 = c & 15;
    size_t row = (size_t)b * T_DIM + s0 + r;
    float4 ka = *(const float4*)(k + row * D_DIM + c8 * 8);
    float4 kb2 = *(const float4*)(k + row * D_DIM + c8 * 8 + 4);
    short8 ko = { (short)f2bf(ka.x), (short)f2bf(ka.y), (short)f2bf(ka.z), (short)f2bf(ka.w),
                  (short)f2bf(kb2.x), (short)f2bf(kb2.y), (short)f2bf(kb2.z), (short)f2bf(kb2.w) };
    *(short8*)(kbf + row * D_DIM + c8 * 8) = ko;
    const float* qr = q + row * D_DIM;
    float e[9];
    float4 f0 = *(const float4*)(qr + c8 * 8);
    float4 f1 = *(const float4*)(qr + c8 * 8 + 4);
    e[0] = f0.x; e[1] = f0.y; e[2] = f0.z; e[3] = f0.w;
    e[4] = f1.x; e[5] = f1.y; e[6] = f1.z; e[7] = f1.w;
    e[8] = qr[(c8 * 8 + 8) & 127];
    short8 qo;
#pragma unroll
    for (int j = 0; j < 8; ++j) qo[j] = (short)f2bf(ca * e[j] + cb * e[j + 1]);
    *(short8*)(qbf + row * D_DIM + c8 * 8) = qo;
    float4 va = *(const float4*)(v + row * D_DIM + c8 * 8);
    float4 vb2 = *(const float4*)(v + row * D_DIM + c8 * 8 + 4);
    short8 vo = { (short)f2bf(va.x), (short)f2bf(va.y), (short)f2bf(va.z), (short)f2bf(va.w),
                  (short)f2bf(vb2.x), (short)f2bf(vb2.y), (short)f2bf(vb2.z), (short)f2bf(vb2.w) };
    *(short8*)(tile + r * 136 + c8 * 8) = vo;
  }
  __syncthreads();
#pragma unroll
  for (int u = 0; u < 8; ++u) {
    int c = u * 256 + tid;                    // 2048 = 128 d x 16 s-quads
    int d = c >> 4, sq = c & 15;
    ushort4 o = { tile[(sq * 4 + 0) * 136 + d], tile[(sq * 4 + 1) * 136 + d],
                  tile[(sq * 4 + 2) * 136 + d], tile[(sq * 4 + 3) * 136 + d] };
    *(ushort4*)(vt + ((size_t)b * D_DIM + d) * T_DIM + s0 + sq * 4) = o;
  }
}

// ---------------- main attention: 2-wave blocks, 64 q-rows, KVBLK=32, dbuf ----------------
// LDS 36,864B: K dbuf 2x8KB | V dbuf 2x8KB | P per-wave 2x2KB ([mt][16][64B] swz)
__global__ __launch_bounds__(128, 2) void attn_kernel(
    const unsigned short* __restrict__ qbf, const unsigned short* __restrict__ kbf,
    const unsigned short* __restrict__ vt, float* __restrict__ out,
    unsigned short* __restrict__ po, float* __restrict__ ml)
{
  __shared__ uint4 smem4[2304];               // 36,864 B
  char* smem = (char*)smem4;
  const int tid = threadIdx.x;
  const int w = tid >> 6, lane = tid & 63;
  const int t16 = lane & 15, g = lane >> 4;
  const int b = blockIdx.x;                   // linear%8==b -> batch pinned to XCD
  const int c = 31 - (int)blockIdx.y;         // 64-row q-chunk, big first
  const int s = blockIdx.z;
  const int nt = 2 * c + 2;                   // causal 32-kv tiles
  const int nseg = (c + 4) >> 2;              // ceil(nt/8)
  if (s >= nseg) return;
  const int t0 = s * SEGT;
  const int t1 = min(nt, t0 + SEGT);
  const int qbw = c * 64 + w * 32;            // wave's first q-row (covers 32 rows)

  char* pw = smem + 32768 + w * 2048;         // per-wave P
  const unsigned short* kbase = kbf + (size_t)b * T_DIM * D_DIM;
  const unsigned short* vbase = vt + (size_t)b * D_DIM * T_DIM;

  // ---- Qeff fragments (A-layout: row=t16, k=dd*32+g*8+i), 2 row-tiles ----
  short8 qf[2][4];
#pragma unroll
  for (int mt = 0; mt < 2; ++mt) {
    const unsigned short* qr = qbf + ((size_t)b * T_DIM + qbw + mt * 16 + t16) * D_DIM + g * 8;
#pragma unroll
    for (int dd = 0; dd < 4; ++dd) qf[mt][dd] = *(const short8*)(qr + dd * 32);
  }

  f32x4 acc[2][8];                            // C: row q = mt*16+4g+r, col d = 16dt+t16
#pragma unroll
  for (int mt = 0; mt < 2; ++mt)
#pragma unroll
    for (int dt = 0; dt < 8; ++dt) acc[mt][dt] = (f32x4){0.f, 0.f, 0.f, 0.f};
  float mrun[2][4], lsum[2][4];               // log2 units
#pragma unroll
  for (int mt = 0; mt < 2; ++mt)
#pragma unroll
    for (int r = 0; r < 4; ++r) { mrun[mt][r] = -1e30f; lsum[mt][r] = 0.f; }

  // ---- staging: wave w half of K (16 rows) and V (64 d-rows) ----
  auto stage = [&](int cur, int kt) {
    const int kv0 = kt * 32;
    char* kb = smem + cur * 8192;
    char* vb = smem + 16384 + cur * 8192;
#pragma unroll
    for (int u = 0; u < 4; ++u) {             // K rows w*16 .. +15 (256B rows, swz)
      int s_loc = w * 16 + u * 4 + (lane >> 4);
      int slot = (lane & 15) ^ (s_loc & 7);
      gload_lds16(kbase + (size_t)(kv0 + s_loc) * D_DIM + slot * 8,
                  kb + w * 4096 + u * 1024);
    }
#pragma unroll
    for (int u = 0; u < 4; ++u) {             // V d-rows w*64 .. +63 (64B rows, swz)
      int d_loc = w * 64 + u * 16 + (lane >> 2);
      int vslot = (lane & 3) ^ (d_loc & 3);
      gload_lds16(vbase + (size_t)d_loc * T_DIM + kv0 + vslot * 8,
                  vb + w * 4096 + u * 1024);
    }
  };

  stage(0, t0);
  __syncthreads();                            // first tile staged (vmcnt drained)
  int cur = 0;

  for (int kt = t0; kt < t1; ++kt) {
    if (kt + 1 < t1) stage(cur ^ 1, kt + 1);  // prefetch overlaps compute
    const int kv0 = kt * 32;

    if (kv0 <= qbw + 31) {                    // wave-causal: skip beyond-diagonal
      char* kb = smem + cur * 8192;
      char* vb = smem + 16384 + cur * 8192;

      // ---- S = Qeff . K^T : sj[mt][jt][r] = S[q][kv=kv0+16jt+t16] ----
      f32x4 sj[2][2];
#pragma unroll
      for (int jt = 0; jt < 2; ++jt) {
        int srow = jt * 16 + t16;
        int rb = srow * 256, swz = (srow & 7) << 4;
        f32x4 s0 = (f32x4){0.f, 0.f, 0.f, 0.f};
        f32x4 s1 = (f32x4){0.f, 0.f, 0.f, 0.f};
#pragma unroll
        for (int dd = 0; dd < 4; ++dd) {
          short8 kf = *(const short8*)(kb + ((rb + dd * 64 + g * 16) ^ swz));
          s0 = __builtin_amdgcn_mfma_f32_16x16x32_bf16(qf[0][dd], kf, s0, 0, 0, 0);
          s1 = __builtin_amdgcn_mfma_f32_16x16x32_bf16(qf[1][dd], kf, s1, 0, 0, 0);
        }
        sj[0][jt] = s0; sj[1][jt] = s1;
      }

      // ---- causal mask (only tile kv0 == qbw is partial) ----
      if (kv0 == qbw) {
#pragma unroll
        for (int mt = 0; mt < 2; ++mt)
#pragma unroll
          for (int jt = 0; jt < 2; ++jt) {
            int sg = kv0 + jt * 16 + t16;
#pragma unroll
            for (int r = 0; r < 4; ++r) {
              int tg = qbw + mt * 16 + 4 * g + r;
              if (sg > tg) sj[mt][jt][r] = -1e30f;
            }
          }
      }

      // ---- defer-max online softmax (log2 domain) ----
      float lm[2][4];
      int ok = 1;
#pragma unroll
      for (int mt = 0; mt < 2; ++mt)
#pragma unroll
        for (int r = 0; r < 4; ++r) {
          lm[mt][r] = fmaxf(sj[mt][0][r], sj[mt][1][r]);
          ok &= (lm[mt][r] <= mrun[mt][r] + 11.0f);
        }
      if (!__all(ok)) {
#pragma unroll
        for (int mt = 0; mt < 2; ++mt)
#pragma unroll
          for (int r = 0; r < 4; ++r) {
            float tm = lm[mt][r];
            tm = fmaxf(tm, __shfl_xor(tm, 1));
            tm = fmaxf(tm, __shfl_xor(tm, 2));
            tm = fmaxf(tm, __shfl_xor(tm, 4));
            tm = fmaxf(tm, __shfl_xor(tm, 8));
            float mnew = fmaxf(mrun[mt][r], tm);
            float corr = exp2f(mrun[mt][r] - mnew);
            mrun[mt][r] = mnew;
            lsum[mt][r] *= corr;
#pragma unroll
            for (int dt = 0; dt < 8; ++dt) acc[mt][dt][r] *= corr;
          }
      }

      // ---- P = exp2(S-m), per-lane partial sums, P -> LDS (swizzled) ----
#pragma unroll
      for (int mt = 0; mt < 2; ++mt)
#pragma unroll
        for (int jt = 0; jt < 2; ++jt)
#pragma unroll
          for (int r = 0; r < 4; ++r) {
            float p = exp2f(sj[mt][jt][r] - mrun[mt][r]);
            lsum[mt][r] += p;
            int row = 4 * g + r;
            *(unsigned short*)(pw + mt * 1024 + row * 64 +
                               ((jt * 32 + t16 * 2) ^ ((row >> 2) << 4))) = f2bf(p);
          }

      // ---- O += P . V (k = 32 = whole tile; vf shared across mt) ----
      short8 pf0 = *(const short8*)(pw + t16 * 64 + ((g * 16) ^ ((t16 >> 2) << 4)));
      short8 pf1 = *(const short8*)(pw + 1024 + t16 * 64 + ((g * 16) ^ ((t16 >> 2) << 4)));
#pragma unroll
      for (int dt = 0; dt < 8; ++dt) {
        int d = dt * 16 + t16;
        short8 vf = *(const short8*)(vb + d * 64 + ((g * 16) ^ ((d & 3) << 4)));
        acc[0][dt] = __builtin_amdgcn_mfma_f32_16x16x32_bf16(pf0, vf, acc[0][dt], 0, 0, 0);
        acc[1][dt] = __builtin_amdgcn_mfma_f32_16x16x32_bf16(pf1, vf, acc[1][dt], 0, 0, 0);
      }
    }

    __syncthreads();                          // prefetch landed + reads of cur done
    cur ^= 1;
  }

  // ---- deferred row-sum reduction (once) ----
  float lred[2][4];
#pragma unroll
  for (int mt = 0; mt < 2; ++mt)
#pragma unroll
    for (int r = 0; r < 4; ++r) {
      float v0 = lsum[mt][r];
      v0 += __shfl_xor(v0, 1);
      v0 += __shfl_xor(v0, 2);
      v0 += __shfl_xor(v0, 4);
      v0 += __shfl_xor(v0, 8);
      lred[mt][r] = v0;
    }

  // ---- epilogue ----
  if (nseg == 1) {
#pragma unroll
    for (int mt = 0; mt < 2; ++mt)
#pragma unroll
      for (int r = 0; r < 4; ++r) {
        float inv = 1.0f / lred[mt][r];
#pragma unroll
        for (int dt = 0; dt < 8; ++dt)
          out[((size_t)b * T_DIM + qbw + mt * 16 + 4 * g + r) * D_DIM + dt * 16 + t16] =
              acc[mt][dt][r] * inv;
      }
  } else {
    int pofs = 0;                             // sum over cc<c of (nseg(cc)-1)
    for (int cc = 0; cc < c; ++cc) pofs += ((cc + 4) >> 2) - 1;
    if (s == 0) {
      // seg0 partial (unnormalized f32) lives in out[]
#pragma unroll
      for (int mt = 0; mt < 2; ++mt)
#pragma unroll
        for (int r = 0; r < 4; ++r)
#pragma unroll
          for (int dt = 0; dt < 8; ++dt)
            out[((size_t)b * T_DIM + qbw + mt * 16 + 4 * g + r) * D_DIM + dt * 16 + t16] =
                acc[mt][dt][r];
    } else {
      unsigned short* pob = po + ((size_t)b * POSLOTS_PER_B + pofs + (s - 1)) * 8192;
#pragma unroll
      for (int mt = 0; mt < 2; ++mt)
#pragma unroll
        for (int r = 0; r < 4; ++r) {
          int rb = w * 32 + mt * 16 + 4 * g + r;  // row within 64-row block
#pragma unroll
          for (int dt = 0; dt < 8; ++dt)
            pob[rb * 128 + dt * 16 + t16] = f2bf(acc[mt][dt][r]);
        }
    }
    if (t16 == 0) {
      const size_t mlslot = (size_t)b * MLSLOTS_PER_B + pofs + c + s;
#pragma unroll
      for (int mt = 0; mt < 2; ++mt)
#pragma unroll
        for (int r = 0; r < 4; ++r) {
          int rb = w * 32 + mt * 16 + 4 * g + r;
          ml[mlslot * 128 + rb] = mrun[mt][r];      // log2 units
          ml[mlslot * 128 + 64 + rb] = lred[mt][r];
        }
    }
  }
}

// ---------------- combine partials (chunks c >= 4); m in log2 units ----------------
__global__ __launch_bounds__(256) void combine_kernel(
    const unsigned short* __restrict__ po, const float* __restrict__ ml,
    float* __restrict__ out)
{
  const int tid = threadIdx.x;
  const int b = blockIdx.x;
  const int c = 4 + (int)blockIdx.y;          // 4..31
  const int nseg = (c + 4) >> 2;              // 2..8
  int pofs = 0;
  for (int cc = 0; cc < c; ++cc) pofs += ((cc + 4) >> 2) - 1;
  const size_t mlbase = (size_t)b * MLSLOTS_PER_B + pofs + c;
  const size_t pobase = (size_t)b * POSLOTS_PER_B + pofs;

  __shared__ float wgt[64][8];
  if (tid < 64) {
    float M = -1e30f;
    for (int s = 0; s < nseg; ++s)
      M = fmaxf(M, ml[(mlbase + s) * 128 + tid]);
    float L = 0.f;
    for (int s = 0; s < nseg; ++s) {
      float e = exp2f(ml[(mlbase + s) * 128 + tid] - M);
      wgt[tid][s] = e;
      L += e * ml[(mlbase + s) * 128 + 64 + tid];
    }
    float invL = 1.f / L;
    for (int s = 0; s < nseg; ++s) wgt[tid][s] *= invL;
  }
  __syncthreads();

#pragma unroll
  for (int it = 0; it < 4; ++it) {
    int vid = it * 256 + tid;                 // 1024 = 64 rows x 16 chunks of 8
    int r = vid >> 4, ch = vid & 15;
    float* op = out + ((size_t)b * T_DIM + c * 64 + r) * D_DIM + ch * 8;
    float4 a0 = *(const float4*)op;
    float4 a1 = *(const float4*)(op + 4);
    float w0 = wgt[r][0];
    float o[8] = { w0 * a0.x, w0 * a0.y, w0 * a0.z, w0 * a0.w,
                   w0 * a1.x, w0 * a1.y, w0 * a1.z, w0 * a1.w };
    for (int s = 1; s < nseg; ++s) {
      short8 pv = *(const short8*)(po + (pobase + s - 1) * 8192 + r * 128 + ch * 8);
      float ws = wgt[r][s];
#pragma unroll
      for (int j = 0; j < 8; ++j) o[j] += ws * bf2f((unsigned short)pv[j]);
    }
    *(float4*)op = (float4){o[0], o[1], o[2], o[3]};
    *(float4*)(op + 4) = (float4){o[4], o[5], o[6], o[7]};
  }
}

extern "C" void kernel_launch(void* const* d_in, const int* in_sizes, int n_in,
                              void* d_out, int out_size, void* d_ws, size_t ws_size,
                              hipStream_t stream) {
  const float* q = (const float*)d_in[0];
  const float* k = (const float*)d_in[1];
  const float* v = (const float*)d_in[2];
  // d_in[3] = mask (causal tril, hardcoded)
  const float* mode = (const float*)d_in[4];
  float* out = (float*)d_out;

  char* ws = (char*)d_ws;
  unsigned short* qbf = (unsigned short*)(ws);                 //  4,194,304
  unsigned short* kbf = (unsigned short*)(ws + 4194304);       //  4,194,304
  unsigned short* vtb = (unsigned short*)(ws + 8388608);       //  4,194,304
  unsigned short* po  = (unsigned short*)(ws + 12582912);      //  8*112 slots * 16KB = 14,680,064
  float*          ml  = (float*)(ws + 27262976);               //  8*144 slots * 512B =   589,824
  // total 27,852,800 B (<= 32,047,104 confirmed available)

  prep_all<<<dim3(B_DIM, T_DIM / 64), 256, 0, stream>>>(q, k, v, mode, qbf, kbf, vtb);
  attn_kernel<<<dim3(B_DIM, 32, SEGT), 128, 0, stream>>>(qbf, kbf, vtb, out, po, ml);
  combine_kernel<<<dim3(B_DIM, 28), 256, 0, stream>>>(po, ml, out);
}